// Round 2
// baseline (121.381 us; speedup 1.0000x reference)
//
#include <hip/hip_runtime.h>

// SparseUnpool2d: out[b,c,h,w] = (pooled[b,c,h/2,w/2] > 0.5f) ? sparse[b,c,h,w] : 0
// B=16, C=64, PH=PW=128, S=2, H=W=256.
// Memory-bound: 604 MB traffic/call -> floor ~96us @ 6.3 TB/s mixed R/W.
// This version: 32B/lane (2x float4) + nontemporal on the streaming pair.

#define PH_ 128
#define PW_ 128
#define H_  256
#define W_  256

typedef float  f32x4 __attribute__((ext_vector_type(4)));

__global__ __launch_bounds__(256) void sparse_unpool_kernel(
    const float* __restrict__ pooled,   // [B,C,PH,PW]
    const float* __restrict__ sparse,   // [B,C,H,W]
    float* __restrict__ out,            // [B,C,H,W]
    long long n8)                       // number of 8-float chunks = B*C*H*W/8
{
    const long long stride = (long long)gridDim.x * blockDim.x;
    for (long long i8 = (long long)blockIdx.x * blockDim.x + threadIdx.x;
         i8 < n8; i8 += stride) {
        // Each chunk = 8 consecutive floats along W. W=256 -> 32 chunks/row.
        const long long row = i8 >> 5;          // bc*H + h
        const int w8  = (int)(i8 & 31);         // chunk index within row
        const int h   = (int)(row & (H_ - 1));
        const long long bc = row >> 8;

        // 8 output w -> 4 pooled w: one float4 pooled load (cached; h-row reuse via L2)
        const long long poff = bc * (PH_ * PW_) + (long long)(h >> 1) * PW_ + (w8 << 2);
        const f32x4 p = *reinterpret_cast<const f32x4*>(pooled + poff);

        const long long soff = i8 << 3;
        const f32x4 s0 = __builtin_nontemporal_load(reinterpret_cast<const f32x4*>(sparse + soff));
        const f32x4 s1 = __builtin_nontemporal_load(reinterpret_cast<const f32x4*>(sparse + soff + 4));

        f32x4 o0, o1;
        o0.x = (p.x > 0.5f) ? s0.x : 0.0f;
        o0.y = (p.x > 0.5f) ? s0.y : 0.0f;
        o0.z = (p.y > 0.5f) ? s0.z : 0.0f;
        o0.w = (p.y > 0.5f) ? s0.w : 0.0f;
        o1.x = (p.z > 0.5f) ? s1.x : 0.0f;
        o1.y = (p.z > 0.5f) ? s1.y : 0.0f;
        o1.z = (p.w > 0.5f) ? s1.z : 0.0f;
        o1.w = (p.w > 0.5f) ? s1.w : 0.0f;

        __builtin_nontemporal_store(o0, reinterpret_cast<f32x4*>(out + soff));
        __builtin_nontemporal_store(o1, reinterpret_cast<f32x4*>(out + soff + 4));
    }
}

extern "C" void kernel_launch(void* const* d_in, const int* in_sizes, int n_in,
                              void* d_out, int out_size, void* d_ws, size_t ws_size,
                              hipStream_t stream) {
    const float* pooled = (const float*)d_in[0];
    const float* sparse = (const float*)d_in[1];
    float* out = (float*)d_out;

    const long long n8 = (long long)out_size / 8;   // 8,388,608
    const int block = 256;
    const int grid = 2048;  // grid-stride x16
    sparse_unpool_kernel<<<grid, block, 0, stream>>>(pooled, sparse, out, n8);
}

// Round 3
// 106.866 us; speedup vs baseline: 1.1358x; 1.1358x over previous
//
#include <hip/hip_runtime.h>

// SparseUnpool2d: out[b,c,h,w] = (pooled[b,c,h/2,w/2] > 0.5f) ? sparse[b,c,h,w] : 0
// B=16, C=64, PH=PW=128, S=2, H=W=256.  604 MB traffic/call -> floor ~96us @ 6.3 TB/s.
// Round 3: copy-ubench-shaped schedule. One-shot map, block-contiguous 16KB tiles,
// batch all loads before stores, plain cached accesses, 32-bit addressing.

#define PH_ 128
#define PW_ 128
#define H_  256
#define W_  256

typedef float f32x4 __attribute__((ext_vector_type(4)));
typedef float f32x2 __attribute__((ext_vector_type(2)));

__global__ __launch_bounds__(256) void sparse_unpool_kernel(
    const float* __restrict__ pooled,   // [B,C,PH,PW]
    const float* __restrict__ sparse,   // [B,C,H,W]
    float* __restrict__ out)            // [B,C,H,W]
{
    // Block tile: 1024 float4 = 16 KB contiguous. Thread t handles float4s
    // g = blk*1024 + k*256 + t, k=0..3  -> each load instr is 4 KB wave-contiguous.
    const unsigned t  = threadIdx.x;
    const unsigned g0 = blockIdx.x * 1024u + t;

    f32x4 s[4];
    f32x2 p[4];
    unsigned gk[4];

    #pragma unroll
    for (int k = 0; k < 4; ++k) {
        const unsigned g = g0 + (unsigned)k * 256u;
        gk[k] = g;
        s[k] = *reinterpret_cast<const f32x4*>(sparse + ((size_t)g << 2));
    }
    #pragma unroll
    for (int k = 0; k < 4; ++k) {
        const unsigned g   = gk[k];
        const unsigned row = g >> 6;            // bc*H + h   (64 float4 per row)
        const unsigned w4  = g & 63u;
        const unsigned h   = row & (H_ - 1u);
        const unsigned bc  = row >> 8;
        const unsigned poff = bc * (PH_ * PW_) + (h >> 1) * PW_ + (w4 << 1);
        p[k] = *reinterpret_cast<const f32x2*>(pooled + poff);
    }

    #pragma unroll
    for (int k = 0; k < 4; ++k) {
        f32x4 o;
        o.x = (p[k].x > 0.5f) ? s[k].x : 0.0f;
        o.y = (p[k].x > 0.5f) ? s[k].y : 0.0f;
        o.z = (p[k].y > 0.5f) ? s[k].z : 0.0f;
        o.w = (p[k].y > 0.5f) ? s[k].w : 0.0f;
        *reinterpret_cast<f32x4*>(out + ((size_t)gk[k] << 2)) = o;
    }
}

extern "C" void kernel_launch(void* const* d_in, const int* in_sizes, int n_in,
                              void* d_out, int out_size, void* d_ws, size_t ws_size,
                              hipStream_t stream) {
    const float* pooled = (const float*)d_in[0];
    const float* sparse = (const float*)d_in[1];
    float* out = (float*)d_out;

    // out_size = 16*64*256*256 = 67,108,864 floats = 16,777,216 float4
    // 1024 float4 per block -> 16384 blocks, one shot (no loop).
    const int block = 256;
    const int grid = out_size / (1024 * 4) + ((out_size % 4096) ? 1 : 0);
    sparse_unpool_kernel<<<grid, block, 0, stream>>>(pooled, sparse, out);
}

// Round 4
// 94.820 us; speedup vs baseline: 1.2801x; 1.1270x over previous
//
#include <hip/hip_runtime.h>

// SparseUnpool2d: out[b,c,h,w] = (pooled[b,c,h/2,w/2] > 0.5f) ? sparse[b,c,h,w] : 0
// B=16, C=64, PH=PW=128, S=2, H=W=256.  604 MB traffic/call -> floor ~96us @ 6.3 TB/s.
// Round 4: deepen batch to 8 float4/thread (32KB block tile, 8192 blocks),
// nontemporal on the streaming pair (sparse in, out), cached pooled.

#define PH_ 128
#define PW_ 128
#define H_  256
#define W_  256

typedef float f32x4 __attribute__((ext_vector_type(4)));
typedef float f32x2 __attribute__((ext_vector_type(2)));

__global__ __launch_bounds__(256) void sparse_unpool_kernel(
    const float* __restrict__ pooled,   // [B,C,PH,PW]
    const float* __restrict__ sparse,   // [B,C,H,W]
    float* __restrict__ out)            // [B,C,H,W]
{
    // Block tile: 2048 float4 = 32 KB contiguous. Thread t handles float4s
    // g = blk*2048 + k*256 + t, k=0..7 -> each access is 4 KB wave-contiguous.
    const unsigned t  = threadIdx.x;
    const unsigned g0 = blockIdx.x * 2048u + t;

    f32x4 s[8];
    f32x2 p[8];

    #pragma unroll
    for (int k = 0; k < 8; ++k) {
        const unsigned g = g0 + (unsigned)k * 256u;
        s[k] = __builtin_nontemporal_load(reinterpret_cast<const f32x4*>(sparse + ((size_t)g << 2)));
    }
    #pragma unroll
    for (int k = 0; k < 8; ++k) {
        const unsigned g   = g0 + (unsigned)k * 256u;
        const unsigned row = g >> 6;            // bc*H + h   (64 float4 per row)
        const unsigned w4  = g & 63u;
        const unsigned h   = row & (H_ - 1u);
        const unsigned bc  = row >> 8;
        const unsigned poff = bc * (PH_ * PW_) + (h >> 1) * PW_ + (w4 << 1);
        p[k] = *reinterpret_cast<const f32x2*>(pooled + poff);
    }

    #pragma unroll
    for (int k = 0; k < 8; ++k) {
        const unsigned g = g0 + (unsigned)k * 256u;
        f32x4 o;
        o.x = (p[k].x > 0.5f) ? s[k].x : 0.0f;
        o.y = (p[k].x > 0.5f) ? s[k].y : 0.0f;
        o.z = (p[k].y > 0.5f) ? s[k].z : 0.0f;
        o.w = (p[k].y > 0.5f) ? s[k].w : 0.0f;
        __builtin_nontemporal_store(o, reinterpret_cast<f32x4*>(out + ((size_t)g << 2)));
    }
}

extern "C" void kernel_launch(void* const* d_in, const int* in_sizes, int n_in,
                              void* d_out, int out_size, void* d_ws, size_t ws_size,
                              hipStream_t stream) {
    const float* pooled = (const float*)d_in[0];
    const float* sparse = (const float*)d_in[1];
    float* out = (float*)d_out;

    // out_size = 67,108,864 floats = 16,777,216 float4; 2048 float4/block -> 8192 blocks.
    const int block = 256;
    const int grid = (out_size / 4 + 2047) / 2048;
    sparse_unpool_kernel<<<grid, block, 0, stream>>>(pooled, sparse, out);
}